// Round 1
// baseline (200.396 us; speedup 1.0000x reference)
//
#include <hip/hip_runtime.h>

// ---- types ----
typedef __attribute__((ext_vector_type(8))) short  bf16x8;  // 8 bf16 = 4 VGPR
typedef __attribute__((ext_vector_type(4))) float  f32x4;

static __device__ __forceinline__ unsigned short f2bf(float f) {
    unsigned u = __float_as_uint(f);
    u += 0x7fffu + ((u >> 16) & 1u);      // RNE (inputs are finite)
    return (unsigned short)(u >> 16);
}

// ---------------------------------------------------------------------------
// Prep: At[bn][n][k] = bf16(A[bn][k][n]); 32*128*128 bf16 = 1 MB into d_ws.
// One thread per 16B chunk (8 k-values at fixed n). Reads coalesced along n.
// ---------------------------------------------------------------------------
__global__ __launch_bounds__(256) void prep_at_kernel(
        const float* __restrict__ A, unsigned short* __restrict__ At)
{
    int g   = blockIdx.x * 256 + threadIdx.x;   // 65536 total
    int bn  = g >> 11;                          // 0..31
    int rem = g & 2047;
    int kc  = rem >> 7;                         // 0..15 (k octet)
    int n   = rem & 127;                        // 0..127

    const float* src = A + bn * 16384 + kc * 8 * 128 + n;
    unsigned h[4];
    #pragma unroll
    for (int j = 0; j < 4; ++j) {
        unsigned short lo = f2bf(src[(2 * j    ) * 128]);
        unsigned short hi = f2bf(src[(2 * j + 1) * 128]);
        h[j] = (unsigned)lo | ((unsigned)hi << 16);
    }
    uint4 pk = make_uint4(h[0], h[1], h[2], h[3]);
    *(uint4*)(At + bn * 16384 + n * 128 + kc * 8) = pk;
}

// ---------------------------------------------------------------------------
// Main: grid = 32 bn-blocks x 128 m-tiles (bn = blockIdx>>7 so consecutive
// blocks share the same At block -> L2 hot). 256 thr = 4 waves; wave w owns
// rows [mt*128 + w*32, +32) x all 128 cols of its bn block.
// Per wave: A-operand (v) 8 frags loaded global->reg->bf16; B-operand (At)
// 32 frags from L2; 32 MFMAs... (2 mi x 8 ni x 4 kq). No LDS, no barriers.
// ---------------------------------------------------------------------------
__global__ __launch_bounds__(256) void trans_main_kernel(
        const float* __restrict__ v,  const float* __restrict__ dx,
        const unsigned short* __restrict__ At, const float* __restrict__ Bm,
        const float* __restrict__ bsc, float* __restrict__ out)
{
    const int blk  = blockIdx.x;
    const int bn   = blk >> 7;          // 0..31
    const int mt   = blk & 127;         // 0..127
    const int w    = threadIdx.x >> 6;  // wave 0..3
    const int l    = threadIdx.x & 63;
    const int lr   = l & 15;
    const int lq   = l >> 4;
    const int row0 = mt * 128 + w * 32;

    // ---- load v fragments (M x K operand), convert to bf16 in-register ----
    // a[mi][kq] lane layout: A[m = lr][k = lq*8 + j], j = 0..7 contiguous.
    bf16x8 a[2][4];
    const float* vb = v + (size_t)(row0 + lr) * 4096 + bn * 128 + lq * 8;
    #pragma unroll
    for (int mi = 0; mi < 2; ++mi) {
        #pragma unroll
        for (int kq = 0; kq < 4; ++kq) {
            const float* p = vb + (size_t)mi * 16 * 4096 + kq * 32;
            float4 f0 = *(const float4*)p;
            float4 f1 = *(const float4*)(p + 4);
            union { bf16x8 vv; unsigned short s[8]; } u;
            u.s[0] = f2bf(f0.x); u.s[1] = f2bf(f0.y);
            u.s[2] = f2bf(f0.z); u.s[3] = f2bf(f0.w);
            u.s[4] = f2bf(f1.x); u.s[5] = f2bf(f1.y);
            u.s[6] = f2bf(f1.z); u.s[7] = f2bf(f1.w);
            a[mi][kq] = u.vv;
        }
    }

    f32x4 acc[2][8];
    #pragma unroll
    for (int mi = 0; mi < 2; ++mi)
        #pragma unroll
        for (int ni = 0; ni < 8; ++ni)
            acc[mi][ni] = (f32x4){0.f, 0.f, 0.f, 0.f};

    // ---- K loop: B-frags (K x N operand) from L2-hot At[bn][n][k] ----
    // b lane layout: B[k = lq*8 + j][n = lr]  == At[n = lr][k contiguous].
    const unsigned short* atb = At + bn * 16384 + lr * 128 + lq * 8;
    #pragma unroll
    for (int kq = 0; kq < 4; ++kq) {
        bf16x8 bq[8];
        #pragma unroll
        for (int ni = 0; ni < 8; ++ni)
            bq[ni] = *(const bf16x8*)(atb + ni * 16 * 128 + kq * 32);
        #pragma unroll
        for (int ni = 0; ni < 8; ++ni) {
            acc[0][ni] = __builtin_amdgcn_mfma_f32_16x16x32_bf16(
                             a[0][kq], bq[ni], acc[0][ni], 0, 0, 0);
            acc[1][ni] = __builtin_amdgcn_mfma_f32_16x16x32_bf16(
                             a[1][kq], bq[ni], acc[1][ni], 0, 0, 0);
        }
    }

    // ---- epilogue: + dx @ B^T + b, ReLU, store ----
    // C/D layout (measured): col = lane&15, row = (lane>>4)*4 + reg.
    const float bias = *bsc;
    float2 bc[8];
    #pragma unroll
    for (int ni = 0; ni < 8; ++ni)
        bc[ni] = *(const float2*)(Bm + 2 * (bn * 128 + ni * 16 + lr));

    #pragma unroll
    for (int mi = 0; mi < 2; ++mi) {
        #pragma unroll
        for (int j = 0; j < 4; ++j) {
            const int row = row0 + mi * 16 + lq * 4 + j;
            const float2 d = *(const float2*)(dx + 2 * row);
            float* orow = out + (size_t)row * 4096 + bn * 128 + lr;
            #pragma unroll
            for (int ni = 0; ni < 8; ++ni) {
                float val = acc[mi][ni][j] + d.x * bc[ni].x + d.y * bc[ni].y + bias;
                orow[ni * 16] = fmaxf(val, 0.0f);
            }
        }
    }
}

// ---------------------------------------------------------------------------
extern "C" void kernel_launch(void* const* d_in, const int* in_sizes, int n_in,
                              void* d_out, int out_size, void* d_ws, size_t ws_size,
                              hipStream_t stream)
{
    const float* v  = (const float*)d_in[0];   // [16384, 4096]
    const float* dx = (const float*)d_in[1];   // [16384, 2]
    const float* A  = (const float*)d_in[2];   // [32, 128, 128]
    const float* Bm = (const float*)d_in[3];   // [4096, 2]
    const float* b  = (const float*)d_in[4];   // scalar

    unsigned short* At = (unsigned short*)d_ws; // 1 MB: [32][128 n][128 k] bf16

    prep_at_kernel<<<dim3(256), dim3(256), 0, stream>>>(A, At);
    trans_main_kernel<<<dim3(4096), dim3(256), 0, stream>>>(v, dx, At, Bm, b,
                                                            (float*)d_out);
}

// Round 2
// 107.726 us; speedup vs baseline: 1.8602x; 1.8602x over previous
//
#include <hip/hip_runtime.h>

// ---- types ----
typedef __attribute__((ext_vector_type(8))) short  bf16x8;  // 8 bf16 = 4 VGPR
typedef __attribute__((ext_vector_type(4))) float  f32x4;

static __device__ __forceinline__ unsigned short f2bf(float f) {
    unsigned u = __float_as_uint(f);
    u += 0x7fffu + ((u >> 16) & 1u);      // RNE (inputs are finite)
    return (unsigned short)(u >> 16);
}

// ---------------------------------------------------------------------------
// Prep: At[bn][n][k] = bf16(A[bn][k][n]); 32*128*128 bf16 = 1 MB into d_ws.
// ---------------------------------------------------------------------------
__global__ __launch_bounds__(256) void prep_at_kernel(
        const float* __restrict__ A, unsigned short* __restrict__ At)
{
    int g   = blockIdx.x * 256 + threadIdx.x;   // 65536 total
    int bn  = g >> 11;
    int rem = g & 2047;
    int kc  = rem >> 7;                         // k octet
    int n   = rem & 127;

    const float* src = A + bn * 16384 + kc * 8 * 128 + n;
    unsigned h[4];
    #pragma unroll
    for (int j = 0; j < 4; ++j) {
        unsigned short lo = f2bf(src[(2 * j    ) * 128]);
        unsigned short hi = f2bf(src[(2 * j + 1) * 128]);
        h[j] = (unsigned)lo | ((unsigned)hi << 16);
    }
    uint4 pk = make_uint4(h[0], h[1], h[2], h[3]);
    *(uint4*)(At + bn * 16384 + n * 128 + kc * 8) = pk;
}

// ---------------------------------------------------------------------------
// Main: 512 blocks (2/CU), 512 threads = 8 waves (wm=wid>>2 in {0,1},
// wn=wid&3). Block owns one bn (blockIdx>>4) for all 16 jobs -> At block
// loaded into registers ONCE (bq[4][2] = 32 VGPR/wave).
// v tile (64 rows x 128 f32 = 32 KB) double-buffered in LDS via
// global_load_lds dwordx4; XOR-swizzle (row&7)<<4 on byte offset, applied on
// BOTH the pre-swizzled global source and the ds_read (rule: both-or-neither).
// One __syncthreads per tile: its vmcnt drain completes the prefetch issued
// at loop top (latency hidden under compute+epilogue) and guards buffer swap.
// ---------------------------------------------------------------------------
__global__ __launch_bounds__(512, 4) void trans_main_kernel(
        const float* __restrict__ v,  const float* __restrict__ dx,
        const unsigned short* __restrict__ At, const float* __restrict__ Bm,
        const float* __restrict__ bsc, float* __restrict__ out)
{
    __shared__ float lds[2][64 * 128];          // 64 KB

    const int tid = threadIdx.x;
    const int wid = tid >> 6;
    const int l   = tid & 63;
    const int lr  = l & 15;
    const int lq  = l >> 4;
    const int wm  = wid >> 2;                   // 0..1 (row half)
    const int wn  = wid & 3;                    // 0..3 (col quarter)
    const int bn     = blockIdx.x >> 4;         // 0..31
    const int mtbase = blockIdx.x & 15;

    // ---- At block -> registers, once. b-frag: B[k=lq*8+j][n=col] ----
    bf16x8 bq[4][2];
    const unsigned short* atb = At + bn * 16384 + (wn * 32 + lr) * 128 + lq * 8;
    #pragma unroll
    for (int kq = 0; kq < 4; ++kq)
        #pragma unroll
        for (int ni = 0; ni < 2; ++ni)
            bq[kq][ni] = *(const bf16x8*)(atb + ni * 16 * 128 + kq * 32);

    // ---- epilogue constants (bn fixed for whole block) ----
    const float bias = *bsc;
    const int col0 = bn * 128 + wn * 32;
    float2 bc[2];
    #pragma unroll
    for (int ni = 0; ni < 2; ++ni)
        bc[ni] = *(const float2*)(Bm + 2 * (col0 + ni * 16 + lr));

    // ---- async stage of one 64x128 tile (pre-swizzled source) ----
    auto stage = [&](int buf, int mt) {
        const float* src = v + (size_t)mt * 64 * 4096 + bn * 128;
        #pragma unroll
        for (int it = 0; it < 4; ++it) {
            int c16  = it * 512 + tid;          // 16B-chunk index in tile
            int row  = c16 >> 5;                // 32 chunks per 512B row
            int off  = (c16 & 31) << 4;         // byte offset within row
            int soff = off ^ ((row & 7) << 4);  // inverse-swizzled source
            const float* g = src + (size_t)row * 4096 + (soff >> 2);
            __builtin_amdgcn_global_load_lds(
                (const __attribute__((address_space(1))) unsigned int*)g,
                (__attribute__((address_space(3))) unsigned int*)
                    &lds[buf][c16 * 4],
                16, 0, 0);
        }
    };

    f32x4 acc[2][2];
    #pragma unroll
    for (int mi = 0; mi < 2; ++mi)
        #pragma unroll
        for (int ni = 0; ni < 2; ++ni)
            acc[mi][ni] = (f32x4){0.f, 0.f, 0.f, 0.f};

    stage(0, mtbase);
    __syncthreads();                            // buf0 ready

    for (int j = 0; j < 16; ++j) {
        const int mt = j * 16 + mtbase;
        if (j + 1 < 16) stage((j + 1) & 1, (j + 1) * 16 + mtbase);

        // ---- compute from lds[j&1] ----
        const char* Lb = (const char*)&lds[j & 1][0];
        #pragma unroll
        for (int kq = 0; kq < 4; ++kq) {
            bf16x8 a[2];
            #pragma unroll
            for (int mi = 0; mi < 2; ++mi) {
                const int row  = wm * 32 + mi * 16 + lr;
                const int base = kq * 128 + lq * 32;
                const int m    = (row & 7) << 4;
                float4 f0 = *(const float4*)(Lb + row * 512 + ((base     ) ^ m));
                float4 f1 = *(const float4*)(Lb + row * 512 + ((base + 16) ^ m));
                union { bf16x8 vv; unsigned short s[8]; } u;
                u.s[0] = f2bf(f0.x); u.s[1] = f2bf(f0.y);
                u.s[2] = f2bf(f0.z); u.s[3] = f2bf(f0.w);
                u.s[4] = f2bf(f1.x); u.s[5] = f2bf(f1.y);
                u.s[6] = f2bf(f1.z); u.s[7] = f2bf(f1.w);
                a[mi] = u.vv;
            }
            #pragma unroll
            for (int mi = 0; mi < 2; ++mi)
                #pragma unroll
                for (int ni = 0; ni < 2; ++ni)
                    acc[mi][ni] = __builtin_amdgcn_mfma_f32_16x16x32_bf16(
                                      a[mi], bq[kq][ni], acc[mi][ni], 0, 0, 0);
        }

        // ---- epilogue: + dx @ B^T + b, ReLU, store; reset acc ----
        #pragma unroll
        for (int mi = 0; mi < 2; ++mi) {
            #pragma unroll
            for (int jj = 0; jj < 4; ++jj) {
                const int row = mt * 64 + wm * 32 + mi * 16 + lq * 4 + jj;
                const float2 d = *(const float2*)(dx + 2 * row);
                float* orow = out + (size_t)row * 4096 + col0 + lr;
                #pragma unroll
                for (int ni = 0; ni < 2; ++ni) {
                    float val = acc[mi][ni][jj] + d.x * bc[ni].x
                              + d.y * bc[ni].y + bias;
                    orow[ni * 16] = fmaxf(val, 0.0f);
                }
            }
            #pragma unroll
            for (int ni = 0; ni < 2; ++ni)
                acc[mi][ni] = (f32x4){0.f, 0.f, 0.f, 0.f};
        }

        __syncthreads();    // all reads of lds[j&1] done; next stage complete
    }
}

// ---------------------------------------------------------------------------
extern "C" void kernel_launch(void* const* d_in, const int* in_sizes, int n_in,
                              void* d_out, int out_size, void* d_ws, size_t ws_size,
                              hipStream_t stream)
{
    const float* v  = (const float*)d_in[0];   // [16384, 4096]
    const float* dx = (const float*)d_in[1];   // [16384, 2]
    const float* A  = (const float*)d_in[2];   // [32, 128, 128]
    const float* Bm = (const float*)d_in[3];   // [4096, 2]
    const float* b  = (const float*)d_in[4];   // scalar

    unsigned short* At = (unsigned short*)d_ws; // 1 MB: [32][128 n][128 k] bf16

    prep_at_kernel<<<dim3(256), dim3(256), 0, stream>>>(A, At);
    trans_main_kernel<<<dim3(512), dim3(512), 0, stream>>>(v, dx, At, Bm, b,
                                                           (float*)d_out);
}